// Round 4
// baseline (678.360 us; speedup 1.0000x reference)
//
#include <hip/hip_runtime.h>
#include <hip/hip_bf16.h>

// ---------- types / helpers ----------
typedef __bf16 bf16x8 __attribute__((ext_vector_type(8)));
typedef float  f32x4  __attribute__((ext_vector_type(4)));
typedef unsigned int u32;
typedef u32 u32x4 __attribute__((ext_vector_type(4)));
typedef unsigned short ushort_t;

__device__ inline float bf2f(ushort_t h) {
    union { u32 u; float f; } v; v.u = ((u32)h) << 16; return v.f;
}
__device__ inline ushort_t f2bf(float f) {
    union { float f; u32 u; } v; v.f = f;
    u32 u = v.u;
    return (ushort_t)((u + 0x7fffu + ((u >> 16) & 1u)) >> 16);   // RNE
}
__device__ inline bf16x8 load_bf8(const ushort_t* p) {
    u32x4 u = *reinterpret_cast<const u32x4*>(p);
    return __builtin_bit_cast(bf16x8, u);
}
// dual-dtype loaders for inputs (idx in elements). f32flag=1 -> array is fp32.
__device__ inline bf16x8 load8_in(const void* base, size_t idx, int f32flag) {
    if (!f32flag) return load_bf8((const ushort_t*)base + idx);
    const float* pf = (const float*)base + idx;
    f32x4 a = *reinterpret_cast<const f32x4*>(pf);
    f32x4 b = *reinterpret_cast<const f32x4*>(pf + 4);
    bf16x8 r;
#pragma unroll
    for (int j = 0; j < 4; ++j) { r[j] = (__bf16)a[j]; r[4 + j] = (__bf16)b[j]; }
    return r;
}
__device__ inline float ld_in(const void* base, size_t idx, int f32flag) {
    return f32flag ? ((const float*)base)[idx] : bf2f(((const ushort_t*)base)[idx]);
}

// ---------- swizzled layouts ----------
// Projected arrays live row-keyed XOR-swizzled: elem (row,ch) at row*256 + (ch ^ ((row&15)<<3)).
// XOR acts on 8-elem (16B) granularity so 16B vector IO survives. m0 % 64 == 0 -> local-row key
// equals global-row key.
__device__ inline int pofs(int row, int ch) { return row * 256 + (ch ^ ((row & 15) << 3)); }
// Fused attention halo tile: tr = global_row - (s0-8); key ((tr+8)&15) matches pofs of global row.
__device__ inline int tofs(int tr, int ch) { return tr * 256 + (ch ^ (((tr + 8) & 15) << 3)); }

// flags layout: [0]=q_emb [1]=s_emb [3]=W_lin [4]=b_lin [5]=W_out [6]=b_out [7]=ln_g [8]=ln_b
__device__ inline int f_of(const int* flags, int i) { return i < 0 ? 0 : flags[i]; }
__device__ inline int out_f32(const int* flags) {
    return flags[0] | flags[1] | flags[3] | flags[4] | flags[5] | flags[6] | flags[7] | flags[8];
}

// ---------- kernel 0: dtype detector, one block per array ----------
__global__ __launch_bounds__(256) void detect_all(
    const u32* a0, const u32* a1, const u32* a2, const u32* a3,
    const u32* a4, const u32* a5, const u32* a6, const u32* a7,
    int* __restrict__ flags)
{
    const u32* arrs[8] = {a0, a1, a2, a3, a4, a5, a6, a7};
    const int  ns[8]   = {16384, 16384, 16384, 384, 16384, 384, 384, 384};
    const int  fi[8]   = {0, 1, 3, 4, 5, 6, 7, 8};
    const int  b = blockIdx.x;
    const u32* d = arrs[b];
    const int  n = ns[b];

    const int t = threadIdx.x;
    int cn = 0, co = 0;
    for (int i = t; i < n; i += 256) {
        const u32 w = d[i];
        const u32 e  = (w >> 7) & 0xFF;
        const u32 fe = (w >> 23) & 0xFF;
        cn += (e >= 100 && e <= 135) ? 1 : 0;
        co += (((w & 0xFFFFu) == 0u) && fe >= 100 && fe <= 140) ? 1 : 0;
    }
    __shared__ int sn[256], so[256];
    sn[t] = cn; so[t] = co; __syncthreads();
    for (int o = 128; o; o >>= 1) {
        if (t < o) { sn[t] += sn[t + o]; so[t] += so[t + o]; }
        __syncthreads();
    }
    if (t == 0) {
        const int CN = sn[0], CO = so[0];
        const int is_f32 = (2 * CN < n) && ((2 * CO > n) || (20 * CN > n));
        flags[fi[b]] = is_f32 ? 1 : 0;
    }
}

// ---------- kernel 1: dual-job projection (LDS-staged both directions) ----------
// Grid 1024: job0 only. Grid 2048: blocks [1024,2048) run job1. In-place safe (block-local rows).
__global__ __launch_bounds__(256, 4) void proj2_kernel(
    const void* X0, int xi0, size_t lw0, size_t lb0, ushort_t* __restrict__ Y0,
    const void* X1, int xi1, size_t lw1, size_t lb1, ushort_t* __restrict__ Y1,
    const void* __restrict__ W, const void* __restrict__ Bv, const int* __restrict__ flags)
{
    __shared__ __align__(16) ushort_t tile[64 * 256];   // 32 KB
    const int half = blockIdx.x >> 10;
    const void* X = half ? X1 : X0;
    const int   xi = half ? xi1 : xi0;
    const size_t lw = half ? lw1 : lw0;
    const size_t lb = half ? lb1 : lb0;
    ushort_t* Y = half ? Y1 : Y0;

    const int xf  = f_of(flags, xi);
    const int wf  = flags[3], bfl = flags[4];
    const int tid = threadIdx.x;
    const int m0  = (blockIdx.x & 1023) * 64;

    // stage in: 64 rows x 32 chunks(16B), coalesced, to bf16, swizzled
#pragma unroll
    for (int i = 0; i < 8; ++i) {
        const int c = tid + 256 * i;
        const int row = c >> 5, cc = c & 31;
        bf16x8 v = load8_in(X, (size_t)(m0 + row) * 256 + cc * 8, xf);
        *reinterpret_cast<u32x4*>(&tile[pofs(row, cc * 8)]) = __builtin_bit_cast(u32x4, v);
    }
    __syncthreads();

    const int wave = tid >> 6, lane = tid & 63;
    const int dil  = wave >> 1;
    const int n_off = (wave & 1) * 64;
    const int l15  = lane & 15, quad = lane >> 4;

    f32x4 acc[4][4] = {};
    for (int kc = 0; kc < 4; ++kc) {
        bf16x8 a[4], b[4];
#pragma unroll
        for (int mt = 0; mt < 4; ++mt)
            a[mt] = load_bf8(&tile[pofs(mt * 16 + l15, dil * 128 + kc * 32 + quad * 8)]);
#pragma unroll
        for (int nt = 0; nt < 4; ++nt)
            b[nt] = load8_in(W, lw + (size_t)dil * 16384 +
                             (size_t)(n_off + nt * 16 + l15) * 128 + kc * 32 + quad * 8, wf);
#pragma unroll
        for (int mt = 0; mt < 4; ++mt)
#pragma unroll
            for (int nt = 0; nt < 4; ++nt)
                acc[mt][nt] = __builtin_amdgcn_mfma_f32_16x16x32_bf16(a[mt], b[nt], acc[mt][nt], 0, 0, 0);
    }
    __syncthreads();   // input tile consumed; reuse for output pack

#pragma unroll
    for (int nt = 0; nt < 4; ++nt) {
        const int ncol = n_off + nt * 16 + l15;
        const float bias = ld_in(Bv, lb + dil * 128 + ncol, bfl);
#pragma unroll
        for (int mt = 0; mt < 4; ++mt)
#pragma unroll
            for (int r = 0; r < 4; ++r) {
                const int row = mt * 16 + quad * 4 + r;
                tile[pofs(row, dil * 128 + ncol)] = f2bf(acc[mt][nt][r] + bias);
            }
    }
    __syncthreads();

    // store out: tile (swizzled) -> Y (same swizzle) is a straight linear copy
#pragma unroll
    for (int i = 0; i < 8; ++i) {
        const int c = tid + 256 * i;
        const int row = c >> 5, cc = c & 31;
        *reinterpret_cast<u32x4*>(Y + (size_t)(m0 + row) * 256 + cc * 8) =
            *reinterpret_cast<const u32x4*>(&tile[row * 256 + cc * 8]);
    }
}

// ---------- kernel 2: fused attention + out-proj + bias + residual + LN (+ next-stage proj) ----------
// P, V: bf16 swizzled projections (V==P for stages A/B). R row-major residual.
// If Yp != null: epilogue also computes proj(LN-output, Wl[lwl]) -> Yp (swizzled), and H (if
// non-null) gets the LN output bf16 row-major via coalesced copy. If Yp == null: LN output goes
// to H (bf16 row-major, or fp32 via two-pass LDS staging when of=1).
__global__ __launch_bounds__(256, 4) void fused_attn_oln_kernel(
    const ushort_t* __restrict__ P, const ushort_t* __restrict__ V,
    const void* __restrict__ R, int ri,
    const void* __restrict__ W, size_t lw,
    const void* __restrict__ Bv, size_t lb,
    const void* __restrict__ G, const void* __restrict__ Bt, size_t lg,
    void* __restrict__ H, int h_out,
    void* __restrict__ probs_base,
    const void* __restrict__ Wl, size_t lwl,
    const void* __restrict__ bl, size_t lbl,
    ushort_t* __restrict__ Yp,
    const int* __restrict__ flags)
{
    __shared__ __align__(16) ushort_t tile[80 * 256];   // 40960 B -> 4 blocks/CU
    // lsum/lsq alias halo rows 0-7 (dead after PV): bytes 0..2047 / 2048..4095
    float (*lsum)[64] = (float (*)[64])(&tile[0]);
    float (*lsq)[64]  = (float (*)[64])(&tile[1024]);

    const int wf = flags[5], bvf = flags[6], gf = flags[7], btf = flags[8];
    const int wlf = flags[3], blf = flags[4];
    const int rf = f_of(flags, ri);
    const int og = out_f32(flags);
    const int of = h_out ? og : 0;

    const int tid  = threadIdx.x;
    const int wave = tid >> 6, lane = tid & 63;
    const int l15  = lane & 15, quad = lane >> 4;
    const int m0   = blockIdx.x * 64;
    const int bb   = m0 >> 11;
    const int s0   = m0 & 2047;
    const size_t rowbase = (size_t)bb * 2048;
    const float scale = 0.17677669529663687f;   // 32^-0.5

    // ---- stage P tile: rows s0-8 .. s0+71 (clamped), straight row copies keep swizzle
#pragma unroll
    for (int i = 0; i < 10; ++i) {
        const int c = tid + 256 * i;          // 2560 chunks
        const int tr = c >> 5, cc = c & 31;
        int s = s0 - 8 + tr; s = s < 0 ? 0 : (s > 2047 ? 2047 : s);
        *reinterpret_cast<u32x4*>(&tile[tr * 256 + cc * 8]) =
            *reinterpret_cast<const u32x4*>(P + (rowbase + s) * 256 + cc * 8);
    }
    __syncthreads();

    const int r = lane, g = wave;
    const int s = s0 + r;

    // ---- scores + softmax for both dilations (p kept in regs)
    float p2[2][5];
#pragma unroll
    for (int it = 0; it < 2; ++it) {
        const int dil  = it;
        const int dila = dil ? 1 : 3;         // DILATIONS = (3,1)
        const int ch0  = dil * 128 + g * 8;

        float qv[4][8];
#pragma unroll
        for (int h = 0; h < 4; ++h) {
            bf16x8 t = load_bf8(&tile[tofs(8 + r, ch0 + h * 32)]);
#pragma unroll
            for (int j = 0; j < 8; ++j) qv[h][j] = (float)t[j];
        }
        float sc[5];
#pragma unroll
        for (int kk = 0; kk < 5; ++kk) {
            const int sp = s + (kk - 2) * dila;
            float a = 0.f;
            if (sp >= 0 && sp < 2048) {       // OOB -> score 0 (zero-pad unfold)
                const int tr2 = 8 + r + (kk - 2) * dila;
#pragma unroll
                for (int h = 0; h < 4; ++h) {
                    bf16x8 t = load_bf8(&tile[tofs(tr2, ch0 + h * 32)]);
#pragma unroll
                    for (int j = 0; j < 8; ++j) a += qv[h][j] * (float)t[j];
                }
                a *= scale;
            }
            sc[kk] = a;
        }
        float mx = sc[0];
#pragma unroll
        for (int kk = 1; kk < 5; ++kk) mx = fmaxf(mx, sc[kk]);
        float sum = 0.f;
#pragma unroll
        for (int kk = 0; kk < 5; ++kk) { p2[it][kk] = __expf(sc[kk] - mx); sum += p2[it][kk]; }
        const float inv = 1.f / sum;
#pragma unroll
        for (int kk = 0; kk < 5; ++kk) p2[it][kk] *= inv;

        if (probs_base != nullptr) {
            const size_t pb = 16777216 + ((size_t)((bb * 8 + dil * 4 + g) * 2048 + s)) * 5;
            if (og) {
                float* pp = (float*)probs_base;
#pragma unroll
                for (int kk = 0; kk < 5; ++kk) pp[pb + kk] = p2[it][kk];
            } else {
                ushort_t* pp = (ushort_t*)probs_base;
#pragma unroll
                for (int kk = 0; kk < 5; ++kk) pp[pb + kk] = f2bf(p2[it][kk]);
            }
        }
    }

    // ---- stage C: swap in the V tile (scores already in regs)
    if (V != P) {
        __syncthreads();                      // all score reads done
#pragma unroll
        for (int i = 0; i < 10; ++i) {
            const int c = tid + 256 * i;
            const int tr = c >> 5, cc = c & 31;
            int s2 = s0 - 8 + tr; s2 = s2 < 0 ? 0 : (s2 > 2047 ? 2047 : s2);
            *reinterpret_cast<u32x4*>(&tile[tr * 256 + cc * 8]) =
                *reinterpret_cast<const u32x4*>(V + (rowbase + s2) * 256 + cc * 8);
        }
        __syncthreads();                      // V tile ready
    }

    // ---- PV for both dilations, packed to bf16 words in regs
    u32x4 wpk[2][4];
#pragma unroll
    for (int it = 0; it < 2; ++it) {
        const int dil  = it;
        const int dila = dil ? 1 : 3;
        const int ch0  = dil * 128 + g * 8;
        float o[4][8] = {};
#pragma unroll
        for (int kk = 0; kk < 5; ++kk) {
            const int sp = s + (kk - 2) * dila;
            if (sp < 0 || sp >= 2048) continue;
            const int tr2 = 8 + r + (kk - 2) * dila;
#pragma unroll
            for (int h = 0; h < 4; ++h) {
                bf16x8 t = load_bf8(&tile[tofs(tr2, ch0 + h * 32)]);
#pragma unroll
                for (int j = 0; j < 8; ++j) o[h][j] += p2[it][kk] * (float)t[j];
            }
        }
#pragma unroll
        for (int c = 0; c < 4; ++c) {
            u32x4 w;
#pragma unroll
            for (int t4 = 0; t4 < 4; ++t4) {
                const int d2a = c * 8 + t4 * 2, d2b = d2a + 1;
                const u32 lo = f2bf(o[d2a & 3][d2a >> 2]);
                const u32 hi = f2bf(o[d2b & 3][d2b >> 2]);
                w[t4] = lo | (hi << 16);
            }
            wpk[it][c] = w;
        }
    }
    __syncthreads();                          // ALL tile reads complete

    // write attention outputs into the tile (rows 8..71 = block rows 0..63)
#pragma unroll
    for (int it = 0; it < 2; ++it)
#pragma unroll
        for (int c = 0; c < 4; ++c)
            *reinterpret_cast<u32x4*>(&tile[tofs(8 + r, it * 128 + g * 32 + c * 8)]) = wpk[it][c];
    __syncthreads();                          // attn-out tile ready

    // ---- output GEMM (K=256) + bias + residual + LN ----
    const int n_off = wave * 64;

    f32x4 acc[4][4] = {};
    for (int kc = 0; kc < 8; ++kc) {
        bf16x8 a[4], b[4];
#pragma unroll
        for (int mt = 0; mt < 4; ++mt)
            a[mt] = load_bf8(&tile[tofs(8 + mt * 16 + l15, kc * 32 + quad * 8)]);
#pragma unroll
        for (int nt = 0; nt < 4; ++nt)
            b[nt] = load8_in(W, lw + (size_t)(n_off + nt * 16 + l15) * 256 + kc * 32 + quad * 8, wf);
#pragma unroll
        for (int mt = 0; mt < 4; ++mt)
#pragma unroll
            for (int nt = 0; nt < 4; ++nt)
                acc[mt][nt] = __builtin_amdgcn_mfma_f32_16x16x32_bf16(a[mt], b[nt], acc[mt][nt], 0, 0, 0);
    }

    float bias[4];
#pragma unroll
    for (int nt = 0; nt < 4; ++nt) bias[nt] = ld_in(Bv, lb + n_off + nt * 16 + l15, bvf);

    float psum[4][4] = {}, psq[4][4] = {};
#pragma unroll
    for (int mt = 0; mt < 4; ++mt) {
#pragma unroll
        for (int rr = 0; rr < 4; ++rr) {
            const size_t rrow = (size_t)(m0 + mt * 16 + quad * 4 + rr) * 256 + l15;
#pragma unroll
            for (int nt = 0; nt < 4; ++nt) {
                float v = acc[mt][nt][rr] + bias[nt] + ld_in(R, rrow + n_off + nt * 16, rf);
                acc[mt][nt][rr] = v;
                psum[mt][rr] += v;
                psq[mt][rr]  += v * v;
            }
        }
    }
#pragma unroll
    for (int off = 1; off <= 8; off <<= 1) {
#pragma unroll
        for (int mt = 0; mt < 4; ++mt)
#pragma unroll
            for (int rr = 0; rr < 4; ++rr) {
                psum[mt][rr] += __shfl_xor(psum[mt][rr], off);
                psq[mt][rr]  += __shfl_xor(psq[mt][rr],  off);
            }
    }
    if (l15 == 0) {
#pragma unroll
        for (int mt = 0; mt < 4; ++mt)
#pragma unroll
            for (int rr = 0; rr < 4; ++rr) {
                const int row = mt * 16 + quad * 4 + rr;
                lsum[wave][row] = psum[mt][rr];
                lsq[wave][row]  = psq[mt][rr];
            }
    }
    __syncthreads();

    float gl[4], blv[4];
#pragma unroll
    for (int nt = 0; nt < 4; ++nt) {
        gl[nt]  = ld_in(G,  lg + n_off + nt * 16 + l15, gf);
        blv[nt] = ld_in(Bt, lg + n_off + nt * 16 + l15, btf);
    }
    // hv into acc (lsum/lsq consumed here)
#pragma unroll
    for (int mt = 0; mt < 4; ++mt) {
#pragma unroll
        for (int rr = 0; rr < 4; ++rr) {
            const int row = mt * 16 + quad * 4 + rr;
            const float sm = lsum[0][row] + lsum[1][row] + lsum[2][row] + lsum[3][row];
            const float q2 = lsq[0][row]  + lsq[1][row]  + lsq[2][row]  + lsq[3][row];
            const float mu  = sm * (1.f / 256.f);
            const float var = q2 * (1.f / 256.f) - mu * mu;
            const float rs  = rsqrtf(var + 1e-5f);
#pragma unroll
            for (int nt = 0; nt < 4; ++nt)
                acc[mt][nt][rr] = (acc[mt][nt][rr] - mu) * rs * gl[nt] + blv[nt];
        }
    }
    __syncthreads();                          // lsum/lsq reads done; full tile reusable

    if (Yp != nullptr) {
        // ---- bf16 LN-output tile (rows 0..63, pofs) ----
#pragma unroll
        for (int mt = 0; mt < 4; ++mt)
#pragma unroll
            for (int rr = 0; rr < 4; ++rr) {
                const int row = mt * 16 + quad * 4 + rr;
#pragma unroll
                for (int nt = 0; nt < 4; ++nt)
                    tile[pofs(row, n_off + nt * 16 + l15)] = f2bf(acc[mt][nt][rr]);
            }
        __syncthreads();

        // optional H copy-out (unswizzle -> row-major bf16), then proj MFMA from tile
        if (H != nullptr) {
#pragma unroll
            for (int i = 0; i < 8; ++i) {
                const int c = tid + 256 * i;
                const int row = c >> 5, cc = c & 31;
                const int sc8 = (cc * 8) ^ ((row & 15) << 3);
                *reinterpret_cast<u32x4*>((ushort_t*)H + (size_t)(m0 + row) * 256 + cc * 8) =
                    *reinterpret_cast<const u32x4*>(&tile[row * 256 + sc8]);
            }
        }
        const int dil2 = wave >> 1;
        const int n2   = (wave & 1) * 64;
        f32x4 pacc[4][4] = {};
        for (int kc = 0; kc < 4; ++kc) {
            bf16x8 a2[4], b2[4];
#pragma unroll
            for (int mt = 0; mt < 4; ++mt)
                a2[mt] = load_bf8(&tile[pofs(mt * 16 + l15, dil2 * 128 + kc * 32 + quad * 8)]);
#pragma unroll
            for (int nt = 0; nt < 4; ++nt)
                b2[nt] = load8_in(Wl, lwl + (size_t)dil2 * 16384 +
                                  (size_t)(n2 + nt * 16 + l15) * 128 + kc * 32 + quad * 8, wlf);
#pragma unroll
            for (int mt = 0; mt < 4; ++mt)
#pragma unroll
                for (int nt = 0; nt < 4; ++nt)
                    pacc[mt][nt] = __builtin_amdgcn_mfma_f32_16x16x32_bf16(a2[mt], b2[nt], pacc[mt][nt], 0, 0, 0);
        }
        __syncthreads();                      // tile reads (copy-out + proj) done

        // pack proj + bias -> tile (pofs)
#pragma unroll
        for (int nt = 0; nt < 4; ++nt) {
            const int ncol = n2 + nt * 16 + l15;
            const float pb = ld_in(bl, lbl + dil2 * 128 + ncol, blf);
#pragma unroll
            for (int mt = 0; mt < 4; ++mt)
#pragma unroll
                for (int r2 = 0; r2 < 4; ++r2)
                    tile[pofs(mt * 16 + quad * 4 + r2, dil2 * 128 + ncol)] = f2bf(pacc[mt][nt][r2] + pb);
        }
        __syncthreads();

        // stream out (swizzle preserved)
#pragma unroll
        for (int i = 0; i < 8; ++i) {
            const int c = tid + 256 * i;
            const int row = c >> 5, cc = c & 31;
            *reinterpret_cast<u32x4*>(Yp + (size_t)(m0 + row) * 256 + cc * 8) =
                *reinterpret_cast<const u32x4*>(&tile[row * 256 + cc * 8]);
        }
    } else if (of) {
        // ---- fp32 H via two-pass LDS staging (coalesced 16B stores) ----
        float* tf = (float*)tile;             // 32 rows x 256 f32 = 32 KB per pass
#pragma unroll
        for (int hh = 0; hh < 2; ++hh) {
#pragma unroll
            for (int mh = 0; mh < 2; ++mh) {
                const int mt = 2 * hh + mh;
#pragma unroll
                for (int rr = 0; rr < 4; ++rr) {
                    const int lrow = mh * 16 + quad * 4 + rr;
#pragma unroll
                    for (int nt = 0; nt < 4; ++nt)
                        tf[lrow * 256 + n_off + nt * 16 + l15] = acc[mt][nt][rr];
                }
            }
            __syncthreads();
#pragma unroll
            for (int i = 0; i < 8; ++i) {
                const int c = tid + 256 * i;      // 2048 chunks: 32 rows x 64 x 16B
                const int row = c >> 6, cc = c & 63;
                *reinterpret_cast<f32x4*>((float*)H + (size_t)(m0 + hh * 32 + row) * 256 + cc * 4) =
                    *reinterpret_cast<const f32x4*>(&tf[row * 256 + cc * 4]);
            }
            __syncthreads();
        }
    } else {
        // ---- bf16 H via LDS staging (coalesced) ----
#pragma unroll
        for (int mt = 0; mt < 4; ++mt)
#pragma unroll
            for (int rr = 0; rr < 4; ++rr) {
                const int row = mt * 16 + quad * 4 + rr;
#pragma unroll
                for (int nt = 0; nt < 4; ++nt)
                    tile[pofs(row, n_off + nt * 16 + l15)] = f2bf(acc[mt][nt][rr]);
            }
        __syncthreads();
#pragma unroll
        for (int i = 0; i < 8; ++i) {
            const int c = tid + 256 * i;
            const int row = c >> 5, cc = c & 31;
            const int sc8 = (cc * 8) ^ ((row & 15) << 3);
            *reinterpret_cast<u32x4*>((ushort_t*)H + (size_t)(m0 + row) * 256 + cc * 8) =
                *reinterpret_cast<const u32x4*>(&tile[row * 256 + sc8]);
        }
    }
}

// ---------- launch ----------
extern "C" void kernel_launch(void* const* d_in, const int* in_sizes, int n_in,
                              void* d_out, int out_size, void* d_ws, size_t ws_size,
                              hipStream_t stream) {
    const void* q_emb = d_in[0];
    const void* s_emb = d_in[1];
    const void* W_lin = d_in[3];   // (3,2,128,128) layer stride 32768 elems
    const void* b_lin = d_in[4];   // (3,2,128)     layer stride 256
    const void* W_out = d_in[5];   // (3,256,256)   layer stride 65536
    const void* b_out = d_in[6];   // (3,256)       layer stride 256
    const void* ln_g  = d_in[7];
    const void* ln_b  = d_in[8];

    const size_t SLOT = 16777216;                      // ushort elems = 33.55 MB
    int*      flags = (int*)d_ws;
    ushort_t* S1 = (ushort_t*)((char*)d_ws + 256);
    ushort_t* S2 = S1 + SLOT;
    ushort_t* S3 = S1 + 2 * SLOT;
    ushort_t* S4 = S1 + 3 * SLOT;
    const size_t need4 = 256 + 4 * SLOT * sizeof(ushort_t);   // 134.2 MB

    const dim3 blk(256);
    detect_all<<<8, blk, 0, stream>>>((const u32*)q_emb, (const u32*)s_emb, (const u32*)W_lin,
        (const u32*)b_lin, (const u32*)W_out, (const u32*)b_out,
        (const u32*)ln_g, (const u32*)ln_b, flags);

    if (ws_size >= need4) {
        // 5-launch schedule: projAB | fusedA(+C-QK proj) | fusedB(+C-V proj) | fusedC
        proj2_kernel<<<2048, blk, 0, stream>>>(q_emb, 0, 0, 0, S1,
                                               s_emb, 1, 32768, 256, S2,
                                               W_lin, b_lin, flags);
        // stage A: hq -> S3 (row-major bf16), SC_C = proj(hq, Wl2) -> S4
        fused_attn_oln_kernel<<<1024, blk, 0, stream>>>(S1, S1, q_emb, 0,
            W_out, 0, b_out, 0, ln_g, ln_b, 0, S3, 0, nullptr,
            W_lin, 65536, b_lin, 512, S4, flags);
        // stage B: hs not stored; SBp = proj(hs, Wl2) -> S1 (SC_A dead); probs -> d_out
        fused_attn_oln_kernel<<<1024, blk, 0, stream>>>(S2, S2, s_emb, 1,
            W_out, 65536, b_out, 256, ln_g, ln_b, 256, nullptr, 0, d_out,
            W_lin, 65536, b_lin, 512, S1, flags);
        // stage C: P=S4, V=S1, R=S3 -> d_out (out dtype)
        fused_attn_oln_kernel<<<1024, blk, 0, stream>>>(S4, S1, S3, -1,
            W_out, 131072, b_out, 512, ln_g, ln_b, 512, d_out, 1, nullptr,
            W_lin, 0, b_lin, 0, nullptr, flags);
    } else {
        // 3-slot fallback (round-2 schedule, 7 launches)
        proj2_kernel<<<1024, blk, 0, stream>>>(q_emb, 0, 0, 0, S1,
                                               q_emb, 0, 0, 0, S1, W_lin, b_lin, flags);
        fused_attn_oln_kernel<<<1024, blk, 0, stream>>>(S1, S1, q_emb, 0,
            W_out, 0, b_out, 0, ln_g, ln_b, 0, S2, 0, nullptr,
            W_lin, 0, b_lin, 0, nullptr, flags);
        proj2_kernel<<<1024, blk, 0, stream>>>(s_emb, 1, 32768, 256, S1,
                                               s_emb, 1, 32768, 256, S1, W_lin, b_lin, flags);
        fused_attn_oln_kernel<<<1024, blk, 0, stream>>>(S1, S1, s_emb, 1,
            W_out, 65536, b_out, 256, ln_g, ln_b, 256, S3, 0, d_out,
            W_lin, 0, b_lin, 0, nullptr, flags);
        proj2_kernel<<<2048, blk, 0, stream>>>(S2, -1, 65536, 512, S1,
                                               S3, -1, 65536, 512, S3, W_lin, b_lin, flags);
        fused_attn_oln_kernel<<<1024, blk, 0, stream>>>(S1, S3, S2, -1,
            W_out, 131072, b_out, 512, ln_g, ln_b, 512, d_out, 1, nullptr,
            W_lin, 0, b_lin, 0, nullptr, flags);
    }
}

// Round 5
// 558.533 us; speedup vs baseline: 1.2145x; 1.2145x over previous
//
#include <hip/hip_runtime.h>
#include <hip/hip_bf16.h>

// ---------- types / helpers ----------
typedef __bf16 bf16x8 __attribute__((ext_vector_type(8)));
typedef float  f32x4  __attribute__((ext_vector_type(4)));
typedef unsigned int u32;
typedef u32 u32x4 __attribute__((ext_vector_type(4)));
typedef unsigned short ushort_t;

__device__ inline float bf2f(ushort_t h) {
    union { u32 u; float f; } v; v.u = ((u32)h) << 16; return v.f;
}
__device__ inline ushort_t f2bf(float f) {
    union { float f; u32 u; } v; v.f = f;
    u32 u = v.u;
    return (ushort_t)((u + 0x7fffu + ((u >> 16) & 1u)) >> 16);   // RNE
}
__device__ inline bf16x8 load_bf8(const ushort_t* p) {
    u32x4 u = *reinterpret_cast<const u32x4*>(p);
    return __builtin_bit_cast(bf16x8, u);
}
// dual-dtype loaders for inputs (idx in elements). f32flag=1 -> array is fp32.
__device__ inline bf16x8 load8_in(const void* base, size_t idx, int f32flag) {
    if (!f32flag) return load_bf8((const ushort_t*)base + idx);
    const float* pf = (const float*)base + idx;
    f32x4 a = *reinterpret_cast<const f32x4*>(pf);
    f32x4 b = *reinterpret_cast<const f32x4*>(pf + 4);
    bf16x8 r;
#pragma unroll
    for (int j = 0; j < 4; ++j) { r[j] = (__bf16)a[j]; r[4 + j] = (__bf16)b[j]; }
    return r;
}
__device__ inline float ld_in(const void* base, size_t idx, int f32flag) {
    return f32flag ? ((const float*)base)[idx] : bf2f(((const ushort_t*)base)[idx]);
}

// ---------- swizzled layouts ----------
// Projected arrays live row-keyed XOR-swizzled: elem (row,ch) at row*256 + (ch ^ ((row&15)<<3)).
// XOR acts on 8-elem (16B) granularity so 16B vector IO survives. m0 % 64 == 0 -> local-row key
// equals global-row key.
__device__ inline int pofs(int row, int ch) { return row * 256 + (ch ^ ((row & 15) << 3)); }
// Fused attention halo tile: tr = global_row - (s0-8); key ((tr+8)&15) matches pofs of global row.
__device__ inline int tofs(int tr, int ch) { return tr * 256 + (ch ^ (((tr + 8) & 15) << 3)); }

// flags layout: [0]=q_emb [1]=s_emb [3]=W_lin [4]=b_lin [5]=W_out [6]=b_out [7]=ln_g [8]=ln_b
__device__ inline int f_of(const int* flags, int i) { return i < 0 ? 0 : flags[i]; }
__device__ inline int out_f32(const int* flags) {
    return flags[0] | flags[1] | flags[3] | flags[4] | flags[5] | flags[6] | flags[7] | flags[8];
}

// ---------- kernel 0: dtype detector, one block per array ----------
__global__ __launch_bounds__(256) void detect_all(
    const u32* a0, const u32* a1, const u32* a2, const u32* a3,
    const u32* a4, const u32* a5, const u32* a6, const u32* a7,
    int* __restrict__ flags)
{
    const u32* arrs[8] = {a0, a1, a2, a3, a4, a5, a6, a7};
    const int  ns[8]   = {16384, 16384, 16384, 384, 16384, 384, 384, 384};
    const int  fi[8]   = {0, 1, 3, 4, 5, 6, 7, 8};
    const int  b = blockIdx.x;
    const u32* d = arrs[b];
    const int  n = ns[b];

    const int t = threadIdx.x;
    int cn = 0, co = 0;
    for (int i = t; i < n; i += 256) {
        const u32 w = d[i];
        const u32 e  = (w >> 7) & 0xFF;
        const u32 fe = (w >> 23) & 0xFF;
        cn += (e >= 100 && e <= 135) ? 1 : 0;
        co += (((w & 0xFFFFu) == 0u) && fe >= 100 && fe <= 140) ? 1 : 0;
    }
    __shared__ int sn[256], so[256];
    sn[t] = cn; so[t] = co; __syncthreads();
    for (int o = 128; o; o >>= 1) {
        if (t < o) { sn[t] += sn[t + o]; so[t] += so[t + o]; }
        __syncthreads();
    }
    if (t == 0) {
        const int CN = sn[0], CO = so[0];
        const int is_f32 = (2 * CN < n) && ((2 * CO > n) || (20 * CN > n));
        flags[fi[b]] = is_f32 ? 1 : 0;
    }
}

// ---------- kernel 1: dual-job projection (LDS-staged both directions) ----------
// Always grid 2048: blocks [0,1024) run job0, [1024,2048) run job1.
// In-place safe (X==Y): stage-in of the block's 64 rows completes (barrier) before any store.
__global__ __launch_bounds__(256, 4) void proj2_kernel(
    const void* X0, int xi0, size_t lw0, size_t lb0, ushort_t* __restrict__ Y0,
    const void* X1, int xi1, size_t lw1, size_t lb1, ushort_t* __restrict__ Y1,
    const void* __restrict__ W, const void* __restrict__ Bv, const int* __restrict__ flags)
{
    __shared__ __align__(16) ushort_t tile[64 * 256];   // 32 KB
    const int half = blockIdx.x >> 10;
    const void* X = half ? X1 : X0;
    const int   xi = half ? xi1 : xi0;
    const size_t lw = half ? lw1 : lw0;
    const size_t lb = half ? lb1 : lb0;
    ushort_t* Y = half ? Y1 : Y0;

    const int xf  = f_of(flags, xi);
    const int wf  = flags[3], bfl = flags[4];
    const int tid = threadIdx.x;
    const int m0  = (blockIdx.x & 1023) * 64;

    // stage in: 64 rows x 32 chunks(16B), coalesced, to bf16, swizzled
#pragma unroll
    for (int i = 0; i < 8; ++i) {
        const int c = tid + 256 * i;
        const int row = c >> 5, cc = c & 31;
        bf16x8 v = load8_in(X, (size_t)(m0 + row) * 256 + cc * 8, xf);
        *reinterpret_cast<u32x4*>(&tile[pofs(row, cc * 8)]) = __builtin_bit_cast(u32x4, v);
    }
    __syncthreads();

    const int wave = tid >> 6, lane = tid & 63;
    const int dil  = wave >> 1;
    const int n_off = (wave & 1) * 64;
    const int l15  = lane & 15, quad = lane >> 4;

    f32x4 acc[4][4] = {};
    for (int kc = 0; kc < 4; ++kc) {
        bf16x8 a[4], b[4];
#pragma unroll
        for (int mt = 0; mt < 4; ++mt)
            a[mt] = load_bf8(&tile[pofs(mt * 16 + l15, dil * 128 + kc * 32 + quad * 8)]);
#pragma unroll
        for (int nt = 0; nt < 4; ++nt)
            b[nt] = load8_in(W, lw + (size_t)dil * 16384 +
                             (size_t)(n_off + nt * 16 + l15) * 128 + kc * 32 + quad * 8, wf);
#pragma unroll
        for (int mt = 0; mt < 4; ++mt)
#pragma unroll
            for (int nt = 0; nt < 4; ++nt)
                acc[mt][nt] = __builtin_amdgcn_mfma_f32_16x16x32_bf16(a[mt], b[nt], acc[mt][nt], 0, 0, 0);
    }
    __syncthreads();   // input tile consumed; reuse for output pack

#pragma unroll
    for (int nt = 0; nt < 4; ++nt) {
        const int ncol = n_off + nt * 16 + l15;
        const float bias = ld_in(Bv, lb + dil * 128 + ncol, bfl);
#pragma unroll
        for (int mt = 0; mt < 4; ++mt)
#pragma unroll
            for (int r = 0; r < 4; ++r) {
                const int row = mt * 16 + quad * 4 + r;
                tile[pofs(row, dil * 128 + ncol)] = f2bf(acc[mt][nt][r] + bias);
            }
    }
    __syncthreads();

    // store out: tile (swizzled) -> Y (same swizzle) is a straight linear copy
#pragma unroll
    for (int i = 0; i < 8; ++i) {
        const int c = tid + 256 * i;
        const int row = c >> 5, cc = c & 31;
        *reinterpret_cast<u32x4*>(Y + (size_t)(m0 + row) * 256 + cc * 8) =
            *reinterpret_cast<const u32x4*>(&tile[row * 256 + cc * 8]);
    }
}

// ---------- kernel 2: fused attention + output proj + bias + residual + LN ----------
// P, V: bf16 swizzled projections (V==P for stages A/B). R row-major residual.
// Attention reads K/V from an LDS-staged 80-row halo tile; results are written back
// into the tile, which then feeds the output GEMM. LDS = 40960 B -> 4 blocks/CU.
__global__ __launch_bounds__(256, 4) void fused_attn_oln_kernel(
    const ushort_t* __restrict__ P, const ushort_t* __restrict__ V,
    const void* __restrict__ R, int ri,
    const void* __restrict__ W, size_t lw,
    const void* __restrict__ Bv, size_t lb,
    const void* __restrict__ G, const void* __restrict__ Bt, size_t lg,
    void* __restrict__ H, int h_out,
    void* __restrict__ probs_base,
    const int* __restrict__ flags)
{
    __shared__ ushort_t tile[80 * 256];   // 40960 B
    // lsum/lsq alias halo rows 0-7 (dead after PV): bytes 0..2047 / 2048..4095
    float (*lsum)[64] = (float (*)[64])(&tile[0]);
    float (*lsq)[64]  = (float (*)[64])(&tile[1024]);

    const int wf = flags[5], bvf = flags[6], gf = flags[7], btf = flags[8];
    const int rf = f_of(flags, ri);
    const int og = out_f32(flags);
    const int of = h_out ? og : 0;

    const int tid  = threadIdx.x;
    const int wave = tid >> 6, lane = tid & 63;
    const int l15  = lane & 15, quad = lane >> 4;
    const int m0   = blockIdx.x * 64;
    const int bb   = m0 >> 11;
    const int s0   = m0 & 2047;
    const size_t rowbase = (size_t)bb * 2048;
    const float scale = 0.17677669529663687f;   // 32^-0.5

    // ---- stage P tile: rows s0-8 .. s0+71 (clamped), straight row copies keep swizzle
#pragma unroll
    for (int i = 0; i < 10; ++i) {
        const int c = tid + 256 * i;          // 2560 chunks
        const int tr = c >> 5, cc = c & 31;
        int s = s0 - 8 + tr; s = s < 0 ? 0 : (s > 2047 ? 2047 : s);
        *reinterpret_cast<u32x4*>(&tile[tr * 256 + cc * 8]) =
            *reinterpret_cast<const u32x4*>(P + (rowbase + s) * 256 + cc * 8);
    }
    __syncthreads();

    const int r = lane, g = wave;
    const int s = s0 + r;

    // ---- scores + softmax for both dilations (p kept in regs)
    float p2[2][5];
#pragma unroll
    for (int it = 0; it < 2; ++it) {
        const int dil  = it;
        const int dila = dil ? 1 : 3;         // DILATIONS = (3,1)
        const int ch0  = dil * 128 + g * 8;

        float qv[4][8];
#pragma unroll
        for (int h = 0; h < 4; ++h) {
            bf16x8 t = load_bf8(&tile[tofs(8 + r, ch0 + h * 32)]);
#pragma unroll
            for (int j = 0; j < 8; ++j) qv[h][j] = (float)t[j];
        }
        float sc[5];
#pragma unroll
        for (int kk = 0; kk < 5; ++kk) {
            const int sp = s + (kk - 2) * dila;
            float a = 0.f;
            if (sp >= 0 && sp < 2048) {       // OOB -> score 0 (zero-pad unfold)
                const int tr2 = 8 + r + (kk - 2) * dila;
#pragma unroll
                for (int h = 0; h < 4; ++h) {
                    bf16x8 t = load_bf8(&tile[tofs(tr2, ch0 + h * 32)]);
#pragma unroll
                    for (int j = 0; j < 8; ++j) a += qv[h][j] * (float)t[j];
                }
                a *= scale;
            }
            sc[kk] = a;
        }
        float mx = sc[0];
#pragma unroll
        for (int kk = 1; kk < 5; ++kk) mx = fmaxf(mx, sc[kk]);
        float sum = 0.f;
#pragma unroll
        for (int kk = 0; kk < 5; ++kk) { p2[it][kk] = __expf(sc[kk] - mx); sum += p2[it][kk]; }
        const float inv = 1.f / sum;
#pragma unroll
        for (int kk = 0; kk < 5; ++kk) p2[it][kk] *= inv;

        if (probs_base != nullptr) {
            const size_t pb = 16777216 + ((size_t)((bb * 8 + dil * 4 + g) * 2048 + s)) * 5;
            if (og) {
                float* pp = (float*)probs_base;
#pragma unroll
                for (int kk = 0; kk < 5; ++kk) pp[pb + kk] = p2[it][kk];
            } else {
                ushort_t* pp = (ushort_t*)probs_base;
#pragma unroll
                for (int kk = 0; kk < 5; ++kk) pp[pb + kk] = f2bf(p2[it][kk]);
            }
        }
    }

    // ---- stage C: swap in the V tile (scores already in regs)
    if (V != P) {
        __syncthreads();                      // all score reads done
#pragma unroll
        for (int i = 0; i < 10; ++i) {
            const int c = tid + 256 * i;
            const int tr = c >> 5, cc = c & 31;
            int s2 = s0 - 8 + tr; s2 = s2 < 0 ? 0 : (s2 > 2047 ? 2047 : s2);
            *reinterpret_cast<u32x4*>(&tile[tr * 256 + cc * 8]) =
                *reinterpret_cast<const u32x4*>(V + (rowbase + s2) * 256 + cc * 8);
        }
        __syncthreads();                      // V tile ready
    }

    // ---- PV for both dilations, packed to bf16 words in regs
    u32x4 wpk[2][4];
#pragma unroll
    for (int it = 0; it < 2; ++it) {
        const int dil  = it;
        const int dila = dil ? 1 : 3;
        const int ch0  = dil * 128 + g * 8;
        float o[4][8] = {};
#pragma unroll
        for (int kk = 0; kk < 5; ++kk) {
            const int sp = s + (kk - 2) * dila;
            if (sp < 0 || sp >= 2048) continue;
            const int tr2 = 8 + r + (kk - 2) * dila;
#pragma unroll
            for (int h = 0; h < 4; ++h) {
                bf16x8 t = load_bf8(&tile[tofs(tr2, ch0 + h * 32)]);
#pragma unroll
                for (int j = 0; j < 8; ++j) o[h][j] += p2[it][kk] * (float)t[j];
            }
        }
#pragma unroll
        for (int c = 0; c < 4; ++c) {
            u32x4 w;
#pragma unroll
            for (int t4 = 0; t4 < 4; ++t4) {
                const int d2a = c * 8 + t4 * 2, d2b = d2a + 1;
                const u32 lo = f2bf(o[d2a & 3][d2a >> 2]);
                const u32 hi = f2bf(o[d2b & 3][d2b >> 2]);
                w[t4] = lo | (hi << 16);
            }
            wpk[it][c] = w;
        }
    }
    __syncthreads();                          // ALL tile reads complete

    // write attention outputs into the tile (rows 8..71 = block rows 0..63)
#pragma unroll
    for (int it = 0; it < 2; ++it)
#pragma unroll
        for (int c = 0; c < 4; ++c)
            *reinterpret_cast<u32x4*>(&tile[tofs(8 + r, it * 128 + g * 32 + c * 8)]) = wpk[it][c];
    __syncthreads();                          // attn-out tile ready

    // ---- output GEMM (K=256) + bias + residual + LN epilogue ----
    const int n_off = wave * 64;

    f32x4 acc[4][4] = {};
    for (int kc = 0; kc < 8; ++kc) {
        bf16x8 a[4], b[4];
#pragma unroll
        for (int mt = 0; mt < 4; ++mt)
            a[mt] = load_bf8(&tile[tofs(8 + mt * 16 + l15, kc * 32 + quad * 8)]);
#pragma unroll
        for (int nt = 0; nt < 4; ++nt)
            b[nt] = load8_in(W, lw + (size_t)(n_off + nt * 16 + l15) * 256 + kc * 32 + quad * 8, wf);
#pragma unroll
        for (int mt = 0; mt < 4; ++mt)
#pragma unroll
            for (int nt = 0; nt < 4; ++nt)
                acc[mt][nt] = __builtin_amdgcn_mfma_f32_16x16x32_bf16(a[mt], b[nt], acc[mt][nt], 0, 0, 0);
    }

    float bias[4];
#pragma unroll
    for (int nt = 0; nt < 4; ++nt) bias[nt] = ld_in(Bv, lb + n_off + nt * 16 + l15, bvf);

    float psum[4][4] = {}, psq[4][4] = {};
#pragma unroll
    for (int mt = 0; mt < 4; ++mt) {
#pragma unroll
        for (int rr = 0; rr < 4; ++rr) {
            const size_t rrow = (size_t)(m0 + mt * 16 + quad * 4 + rr) * 256 + l15;
#pragma unroll
            for (int nt = 0; nt < 4; ++nt) {
                float v = acc[mt][nt][rr] + bias[nt] + ld_in(R, rrow + n_off + nt * 16, rf);
                acc[mt][nt][rr] = v;
                psum[mt][rr] += v;
                psq[mt][rr]  += v * v;
            }
        }
    }
#pragma unroll
    for (int off = 1; off <= 8; off <<= 1) {
#pragma unroll
        for (int mt = 0; mt < 4; ++mt)
#pragma unroll
            for (int rr = 0; rr < 4; ++rr) {
                psum[mt][rr] += __shfl_xor(psum[mt][rr], off);
                psq[mt][rr]  += __shfl_xor(psq[mt][rr],  off);
            }
    }
    if (l15 == 0) {
#pragma unroll
        for (int mt = 0; mt < 4; ++mt)
#pragma unroll
            for (int rr = 0; rr < 4; ++rr) {
                const int row = mt * 16 + quad * 4 + rr;
                lsum[wave][row] = psum[mt][rr];
                lsq[wave][row]  = psq[mt][rr];
            }
    }
    __syncthreads();

    float gl[4], blv[4];
#pragma unroll
    for (int nt = 0; nt < 4; ++nt) {
        gl[nt]  = ld_in(G,  lg + n_off + nt * 16 + l15, gf);
        blv[nt] = ld_in(Bt, lg + n_off + nt * 16 + l15, btf);
    }
#pragma unroll
    for (int mt = 0; mt < 4; ++mt) {
#pragma unroll
        for (int rr = 0; rr < 4; ++rr) {
            const int row = mt * 16 + quad * 4 + rr;
            const float sm = lsum[0][row] + lsum[1][row] + lsum[2][row] + lsum[3][row];
            const float q2 = lsq[0][row]  + lsq[1][row]  + lsq[2][row]  + lsq[3][row];
            const float mu  = sm * (1.f / 256.f);
            const float var = q2 * (1.f / 256.f) - mu * mu;
            const float rs  = rsqrtf(var + 1e-5f);
            const size_t hrow = (size_t)(m0 + row) * 256 + l15;
#pragma unroll
            for (int nt = 0; nt < 4; ++nt) {
                const float hv = (acc[mt][nt][rr] - mu) * rs * gl[nt] + blv[nt];
                if (of) ((float*)H)[hrow + n_off + nt * 16] = hv;
                else    ((ushort_t*)H)[hrow + n_off + nt * 16] = f2bf(hv);
            }
        }
    }
}

// ---------- launch ----------
extern "C" void kernel_launch(void* const* d_in, const int* in_sizes, int n_in,
                              void* d_out, int out_size, void* d_ws, size_t ws_size,
                              hipStream_t stream) {
    const void* q_emb = d_in[0];
    const void* s_emb = d_in[1];
    const void* W_lin = d_in[3];   // (3,2,128,128) layer stride 32768 elems
    const void* b_lin = d_in[4];   // (3,2,128)     layer stride 256
    const void* W_out = d_in[5];   // (3,256,256)   layer stride 65536
    const void* b_out = d_in[6];   // (3,256)       layer stride 256
    const void* ln_g  = d_in[7];
    const void* ln_b  = d_in[8];

    const size_t SLOT = 16777216;                      // ushort elems = 33.55 MB
    int*      flags = (int*)d_ws;
    ushort_t* S1 = (ushort_t*)((char*)d_ws + 256);
    ushort_t* S2 = S1 + SLOT;
    ushort_t* S3 = S1 + 2 * SLOT;
    // d_ws footprint: 256 B + 3 x 33.55 MB = 100.7 MB (round-2 proved resident)

    const dim3 blk(256);
    detect_all<<<8, blk, 0, stream>>>((const u32*)q_emb, (const u32*)s_emb, (const u32*)W_lin,
        (const u32*)b_lin, (const u32*)W_out, (const u32*)b_out,
        (const u32*)ln_g, (const u32*)ln_b, flags);

    // ---- proj A+B concurrently: SC_A = proj(q_emb, Wl0) -> S1 ; SC_B = proj(s_emb, Wl1) -> S2
    proj2_kernel<<<2048, blk, 0, stream>>>(q_emb, 0, 0, 0, S1,
                                           s_emb, 1, 32768, 256, S2,
                                           W_lin, b_lin, flags);
    // ---- stage A: hq = LN(q_emb + attn(SC_A)) -> S3 (bf16 row-major)
    fused_attn_oln_kernel<<<1024, blk, 0, stream>>>(S1, S1, q_emb, 0,
        W_out, 0, b_out, 0, ln_g, ln_b, 0, S3, 0, nullptr, flags);
    // ---- stage B: hs = LN(s_emb + attn(SC_B)) -> S1 (SC_A dead); probs -> d_out[16777216..]
    fused_attn_oln_kernel<<<1024, blk, 0, stream>>>(S2, S2, s_emb, 1,
        W_out, 65536, b_out, 256, ln_g, ln_b, 256, S1, 0, d_out, flags);
    // ---- proj C concurrently: QK = proj(hq=S3, Wl2) -> S2 (SC_B dead); V = proj(hs=S1, Wl2) -> S1 in-place
    proj2_kernel<<<2048, blk, 0, stream>>>(S3, -1, 65536, 512, S2,
                                           S1, -1, 65536, 512, S1,
                                           W_lin, b_lin, flags);
    // ---- stage C: z = LN(hq + attn(P=S2, V=S1)) -> d_out (out dtype)
    fused_attn_oln_kernel<<<1024, blk, 0, stream>>>(S2, S1, S3, -1,
        W_out, 131072, b_out, 512, ln_g, ln_b, 512, d_out, 1, nullptr, flags);
}